// Round 1
// baseline (607.875 us; speedup 1.0000x reference)
//
#include <hip/hip_runtime.h>
#include <hip/hip_bf16.h>

// Soft decision tree, fused MFMA implementation (f16 inputs, fp32 accum).
// BATCH=8192, D_IN=512, H1=128, H2=64, OUT=8, LEAVES=64, INTERNAL=63.

typedef _Float16 f16;
typedef _Float16 f16x8 __attribute__((ext_vector_type(8)));
typedef _Float16 f16x4 __attribute__((ext_vector_type(4)));
typedef float    f32x4 __attribute__((ext_vector_type(4)));

#define MFMA16(a, b, c) __builtin_amdgcn_mfma_f32_16x16x32_f16((a), (b), (c), 0, 0, 0)

// ---------------- workspace layout (bytes) ----------------
#define WS_XH    0u           // 8192*512 f16            = 8,388,608
#define WS_W1T   8388608u     // 64*128*512 f16          = 8,388,608
#define WS_W2T   16777216u    // 64*64*128 f16           = 1,048,576
#define WS_W3T   17825792u    // 64*16*64 f16            =   131,072
#define WS_RWT   17956864u    // 64*512 f16              =    65,536
#define WS_P     18022400u    // 8192*64 f32             = 2,097,152
#define WS_NEED  20119552u

// ---------------- LDS layout for fused kernel (bytes) ----------------
// strides in halfs (padded so row-start bank advances by 4 -> 2-way (free))
#define XS   520   // x tile row stride (512 + 8)
#define WTS  72    // wbuf / w3 row stride (64 + 8)
#define H1S  136   // h1 / w2 row stride (128 + 8)
#define H2S  72    // h2 row stride
#define WCH  9216  // halfs per wbuf buffer (128*72)

#define L_X   0
#define L_WB  66560
#define L_W2  103424
#define L_W3  120832
#define L_H1  123136
#define L_H2  140544
#define L_P   149760
#define L_TOT 153856

// ============ convert x: fp32 -> f16 ============
__global__ __launch_bounds__(256) void convert_x(const float* __restrict__ x,
                                                 f16* __restrict__ xh) {
  int i = (blockIdx.x * 256 + threadIdx.x) * 4;
  float4 v = *(const float4*)(x + i);
  f16x4 h = {(f16)v.x, (f16)v.y, (f16)v.z, (f16)v.w};
  *(f16x4*)(xh + i) = h;
}

// ============ convert router_W [63][512] -> f16 [64][512] (row 63 zero) ============
__global__ __launch_bounds__(256) void convert_rwt(const float* __restrict__ rw,
                                                   f16* __restrict__ rwt) {
  int idx = blockIdx.x * 256 + threadIdx.x;   // 0..32767
  int n = idx >> 9;
  float v = 0.f;
  if (n < 63) v = rw[idx];
  rwt[idx] = (f16)v;
}

// ============ generic transpose: src fp32 [L][K][N] -> dst f16 [L][Npad][K] ============
__global__ __launch_bounds__(256) void transpose_wk(const float* __restrict__ src,
                                                    f16* __restrict__ dst,
                                                    int K, int N, int Npad) {
  __shared__ float tile[64][65];
  int k0 = blockIdx.x * 64;
  int l  = blockIdx.y;
  int n0 = blockIdx.z * 64;
  int t  = threadIdx.x;
  const float* s = src + ((size_t)l * K + k0) * N + n0;
#pragma unroll
  for (int i = 0; i < 16; ++i) {
    int idx = t + i * 256;
    int kk = idx >> 6, nn = idx & 63;
    float v = 0.f;
    if (n0 + nn < N) v = s[(size_t)kk * N + nn];
    tile[kk][nn] = v;
  }
  __syncthreads();
  f16* d = dst + ((size_t)l * Npad + n0) * K + k0;
#pragma unroll
  for (int i = 0; i < 16; ++i) {
    int idx = t + i * 256;
    int nn = idx >> 6, kk = idx & 63;
    if (n0 + nn < Npad) d[(size_t)nn * K + kk] = (f16)tile[kk][nn];
  }
}

// ============ router: logits (MFMA f16) -> sigmoid -> path products p[8192][64] ============
__global__ __launch_bounds__(256) void router_kernel(const f16* __restrict__ xh,
                                                     const f16* __restrict__ rwt,
                                                     const float* __restrict__ rb,
                                                     float* __restrict__ p_out) {
  __shared__ float route_s[64][64];
  const int t = threadIdx.x;
  const int wave = t >> 6, L = t & 63, quad = L >> 4, l16 = L & 15;
  const int b0 = blockIdx.x * 64;

  f32x4 acc[4];
#pragma unroll
  for (int nt = 0; nt < 4; ++nt) acc[nt] = (f32x4){0.f, 0.f, 0.f, 0.f};

  const f16* xrow = xh + (size_t)(b0 + wave * 16 + l16) * 512;
#pragma unroll 4
  for (int kk = 0; kk < 16; ++kk) {
    f16x8 a = *(const f16x8*)(xrow + kk * 32 + quad * 8);
#pragma unroll
    for (int nt = 0; nt < 4; ++nt) {
      f16x8 b = *(const f16x8*)(rwt + (size_t)(nt * 16 + l16) * 512 + kk * 32 + quad * 8);
      acc[nt] = MFMA16(a, b, acc[nt]);
    }
  }
#pragma unroll
  for (int nt = 0; nt < 4; ++nt) {
    int n = nt * 16 + l16;
    float bias = (n < 63) ? rb[n] : 0.f;
#pragma unroll
    for (int rg = 0; rg < 4; ++rg) {
      int r = wave * 16 + quad * 4 + rg;
      float logit = acc[nt][rg] + bias;
      route_s[r][n] = 1.f / (1.f + __expf(-logit));
    }
  }
  __syncthreads();
  // path products: thread -> row = t>>2 (64 rows), 16 leaves each
  int row = t >> 2, lq = t & 3;
#pragma unroll
  for (int j = 0; j < 16; ++j) {
    int l = lq * 16 + j;
    float prod = 1.f;
#pragma unroll
    for (int lev = 0; lev < 6; ++lev) {
      int node = (1 << lev) - 1 + (l >> (6 - lev));
      float d = route_s[row][node];
      prod *= ((l >> (5 - lev)) & 1) ? (1.f - d) : d;
    }
    p_out[(size_t)(b0 + row) * 64 + l] = prod;
  }
}

// ============ fused per-leaf MLP + weighted sum ============
// grid (128 batch-tiles, 4 leaf-groups), 256 threads, dynamic LDS = L_TOT
__global__ __launch_bounds__(256, 1) void fused_tree(
    const f16* __restrict__ xh, const f16* __restrict__ w1t,
    const f16* __restrict__ w2t, const f16* __restrict__ w3t,
    const float* __restrict__ pglob, const float* __restrict__ b1,
    const float* __restrict__ b2, const float* __restrict__ b3,
    float* __restrict__ out) {
  extern __shared__ char smem[];
  f16*   x_lds  = (f16*)(smem + L_X);    // [64][520]
  f16*   wbuf   = (f16*)(smem + L_WB);   // [2][128][72]
  f16*   w2_lds = (f16*)(smem + L_W2);   // [64][136]
  f16*   w3_lds = (f16*)(smem + L_W3);   // [16][72]
  f16*   h1_lds = (f16*)(smem + L_H1);   // [64][136]
  f16*   h2_lds = (f16*)(smem + L_H2);   // [64][72]
  float* p_lds  = (float*)(smem + L_P);  // [64][16]

  const int t = threadIdx.x;
  const int wave = t >> 6, L = t & 63, quad = L >> 4, l16 = L & 15;
  const int mh = wave & 1;   // M-half (GEMM1/2 wave tiling)
  const int nh = wave >> 1;  // N-half
  const int b0  = blockIdx.x * 64;
  const int lg0 = blockIdx.y * 16;

  // stage x tile 64x512 (f16) once
#pragma unroll
  for (int i = 0; i < 16; ++i) {
    int idx = t + i * 256;
    int r = idx >> 6, c8 = idx & 63;
    *(uint4*)(x_lds + r * XS + c8 * 8) = *(const uint4*)(xh + (size_t)(b0 + r) * 512 + c8 * 8);
  }
  // stage p tile 64x16
#pragma unroll
  for (int i = 0; i < 4; ++i) {
    int idx = t + i * 256;
    int r = idx >> 4, li = idx & 15;
    p_lds[r * 16 + li] = pglob[(size_t)(b0 + r) * 64 + lg0 + li];
  }

  f32x4 acc_out = {0.f, 0.f, 0.f, 0.f};  // GEMM3 accumulator, persists over leaves
  __syncthreads();

  for (int li = 0; li < 16; ++li) {
    const int l = lg0 + li;
    const f16* w1l = w1t + (size_t)l * (128 * 512);

    // ---- GEMM1: X(64x512) @ W1t[l] -> H1(64x128) ----
    // prologue: stage chunk 0 (BK=64) into wbuf[0]
#pragma unroll
    for (int a = 0; a < 4; ++a) {
      int idx = t + a * 256;
      int n = idx >> 3, q = idx & 7;
      *(uint4*)(wbuf + n * WTS + q * 8) = *(const uint4*)(w1l + n * 512 + q * 8);
    }
    f32x4 acc1[2][4];
#pragma unroll
    for (int mt = 0; mt < 2; ++mt)
#pragma unroll
      for (int nt = 0; nt < 4; ++nt) acc1[mt][nt] = (f32x4){0.f, 0.f, 0.f, 0.f};
    __syncthreads();

    for (int kk = 0; kk < 8; ++kk) {
      const int cur = kk & 1;
      uint4 pf[4];
      if (kk < 7) {  // prefetch next chunk into regs
        const f16* src = w1l + (kk + 1) * 64;
#pragma unroll
        for (int a = 0; a < 4; ++a) {
          int idx = t + a * 256;
          int n = idx >> 3, q = idx & 7;
          pf[a] = *(const uint4*)(src + n * 512 + q * 8);
        }
      }
#pragma unroll
      for (int ks = 0; ks < 2; ++ks) {
        f16x8 afr[2];
#pragma unroll
        for (int mt = 0; mt < 2; ++mt)
          afr[mt] = *(const f16x8*)(x_lds + (mh * 32 + mt * 16 + l16) * XS + kk * 64 + ks * 32 + quad * 8);
#pragma unroll
        for (int nt = 0; nt < 4; ++nt) {
          f16x8 bfr = *(const f16x8*)(wbuf + cur * WCH + (nh * 64 + nt * 16 + l16) * WTS + ks * 32 + quad * 8);
#pragma unroll
          for (int mt = 0; mt < 2; ++mt) acc1[mt][nt] = MFMA16(afr[mt], bfr, acc1[mt][nt]);
        }
      }
      if (kk < 7) {
        f16* dst = wbuf + (cur ^ 1) * WCH;
#pragma unroll
        for (int a = 0; a < 4; ++a) {
          int idx = t + a * 256;
          int n = idx >> 3, q = idx & 7;
          *(uint4*)(dst + n * WTS + q * 8) = pf[a];
        }
      }
      __syncthreads();
    }

    // H1 epilogue: +b1, relu, f16 -> h1_lds
#pragma unroll
    for (int nt = 0; nt < 4; ++nt) {
      int n = nh * 64 + nt * 16 + l16;
      float bias = b1[l * 128 + n];
#pragma unroll
      for (int mt = 0; mt < 2; ++mt)
#pragma unroll
        for (int rg = 0; rg < 4; ++rg) {
          int r = mh * 32 + mt * 16 + quad * 4 + rg;
          float v = acc1[mt][nt][rg] + bias;
          h1_lds[r * H1S + n] = (f16)(v > 0.f ? v : 0.f);
        }
    }
    // stage W2t[l] (64x128) and W3t[l] (16x64)
    {
      const f16* w2l = w2t + (size_t)l * (64 * 128);
#pragma unroll
      for (int a = 0; a < 4; ++a) {
        int idx = t + a * 256;
        int n = idx >> 4, q = idx & 15;
        *(uint4*)(w2_lds + n * H1S + q * 8) = *(const uint4*)(w2l + n * 128 + q * 8);
      }
      if (t < 128) {
        const f16* w3l = w3t + (size_t)l * (16 * 64);
        int n = t >> 3, q = t & 7;
        *(uint4*)(w3_lds + n * WTS + q * 8) = *(const uint4*)(w3l + n * 64 + q * 8);
      }
    }
    __syncthreads();

    // ---- GEMM2: H1(64x128) @ W2t[l] -> H2(64x64), relu, * p ----
    f32x4 acc2[2][2];
#pragma unroll
    for (int mt = 0; mt < 2; ++mt)
#pragma unroll
      for (int nt = 0; nt < 2; ++nt) acc2[mt][nt] = (f32x4){0.f, 0.f, 0.f, 0.f};
#pragma unroll
    for (int ks = 0; ks < 4; ++ks) {
      f16x8 afr[2];
#pragma unroll
      for (int mt = 0; mt < 2; ++mt)
        afr[mt] = *(const f16x8*)(h1_lds + (mh * 32 + mt * 16 + l16) * H1S + ks * 32 + quad * 8);
#pragma unroll
      for (int nt = 0; nt < 2; ++nt) {
        f16x8 bfr = *(const f16x8*)(w2_lds + (nh * 32 + nt * 16 + l16) * H1S + ks * 32 + quad * 8);
#pragma unroll
        for (int mt = 0; mt < 2; ++mt) acc2[mt][nt] = MFMA16(afr[mt], bfr, acc2[mt][nt]);
      }
    }
    float pv[2][4];
#pragma unroll
    for (int mt = 0; mt < 2; ++mt)
#pragma unroll
      for (int rg = 0; rg < 4; ++rg)
        pv[mt][rg] = p_lds[(mh * 32 + mt * 16 + quad * 4 + rg) * 16 + li];
#pragma unroll
    for (int nt = 0; nt < 2; ++nt) {
      int n = nh * 32 + nt * 16 + l16;
      float bias = b2[l * 64 + n];
#pragma unroll
      for (int mt = 0; mt < 2; ++mt)
#pragma unroll
        for (int rg = 0; rg < 4; ++rg) {
          float v = acc2[mt][nt][rg] + bias;
          v = v > 0.f ? v : 0.f;
          h2_lds[(mh * 32 + mt * 16 + quad * 4 + rg) * H2S + n] = (f16)(v * pv[mt][rg]);
        }
    }
    __syncthreads();

    // ---- GEMM3: H2'(64x64) @ W3t[l] -> acc_out (64x16, cols 8..15 are zero-pad) ----
#pragma unroll
    for (int ks = 0; ks < 2; ++ks) {
      f16x8 afr = *(const f16x8*)(h2_lds + (wave * 16 + l16) * H2S + ks * 32 + quad * 8);
      f16x8 bfr = *(const f16x8*)(w3_lds + l16 * WTS + ks * 32 + quad * 8);
      acc_out = MFMA16(afr, bfr, acc_out);
    }
    // no barrier: next-iter LDS writes (wbuf) are disjoint & protected by their own syncs
  }

  // final epilogue: + sum_l p*b3, atomicAdd into out
  if (l16 < 8) {
    float b3v[16];
#pragma unroll
    for (int li = 0; li < 16; ++li) b3v[li] = b3[(lg0 + li) * 8 + l16];
#pragma unroll
    for (int rg = 0; rg < 4; ++rg) {
      int r = wave * 16 + quad * 4 + rg;
      float v = acc_out[rg];
#pragma unroll
      for (int li = 0; li < 16; ++li) v += p_lds[r * 16 + li] * b3v[li];
      atomicAdd(out + (size_t)(b0 + r) * 8 + l16, v);
    }
  }
}

extern "C" void kernel_launch(void* const* d_in, const int* in_sizes, int n_in,
                              void* d_out, int out_size, void* d_ws, size_t ws_size,
                              hipStream_t stream) {
  const float* x  = (const float*)d_in[0];
  const float* rW = (const float*)d_in[1];
  const float* rb = (const float*)d_in[2];
  const float* W1 = (const float*)d_in[3];
  const float* b1 = (const float*)d_in[4];
  const float* W2 = (const float*)d_in[5];
  const float* b2 = (const float*)d_in[6];
  const float* W3 = (const float*)d_in[7];
  const float* b3 = (const float*)d_in[8];
  float* out = (float*)d_out;

  if (ws_size < WS_NEED) return;  // workspace too small: cannot run safely

  char* ws = (char*)d_ws;
  f16*   xh  = (f16*)(ws + WS_XH);
  f16*   w1t = (f16*)(ws + WS_W1T);
  f16*   w2t = (f16*)(ws + WS_W2T);
  f16*   w3t = (f16*)(ws + WS_W3T);
  f16*   rwt = (f16*)(ws + WS_RWT);
  float* p   = (float*)(ws + WS_P);

  hipMemsetAsync(d_out, 0, (size_t)out_size * sizeof(float), stream);

  convert_x<<<4096, 256, 0, stream>>>(x, xh);
  convert_rwt<<<128, 256, 0, stream>>>(rW, rwt);
  transpose_wk<<<dim3(8, 64, 2), 256, 0, stream>>>(W1, w1t, 512, 128, 128);
  transpose_wk<<<dim3(2, 64, 1), 256, 0, stream>>>(W2, w2t, 128, 64, 64);
  transpose_wk<<<dim3(1, 64, 1), 256, 0, stream>>>(W3, w3t, 64, 8, 16);
  router_kernel<<<128, 256, 0, stream>>>(xh, rwt, rb, p);

  (void)hipFuncSetAttribute(reinterpret_cast<const void*>(fused_tree),
                            hipFuncAttributeMaxDynamicSharedMemorySize, L_TOT);
  fused_tree<<<dim3(128, 4), 256, L_TOT, stream>>>(xh, w1t, w2t, w3t, p, b1, b2, b3, out);
}

// Round 2
// 313.629 us; speedup vs baseline: 1.9382x; 1.9382x over previous
//
#include <hip/hip_runtime.h>
#include <hip/hip_bf16.h>

// Soft decision tree, fused MFMA implementation (f16 inputs, fp32 accum).
// BATCH=8192, D_IN=512, H1=128, H2=64, OUT=8, LEAVES=64, INTERNAL=63.
// R2: 32-row batch tiles, 79 KB LDS -> 2 blocks/CU, global_load_lds staging,
//     XOR-swizzled unpadded LDS for x and W1 chunks, mfma 32x32x16 for GEMM1.

typedef _Float16 f16;
typedef _Float16 f16x8 __attribute__((ext_vector_type(8)));
typedef _Float16 f16x4 __attribute__((ext_vector_type(4)));
typedef float    f32x4 __attribute__((ext_vector_type(4)));
typedef float    f32x16 __attribute__((ext_vector_type(16)));

#define MFMA16(a, b, c) __builtin_amdgcn_mfma_f32_16x16x32_f16((a), (b), (c), 0, 0, 0)
#define MFMA32(a, b, c) __builtin_amdgcn_mfma_f32_32x32x16_f16((a), (b), (c), 0, 0, 0)

// async global->LDS copy, 16 B per lane; LDS dest = wave-uniform base + lane*16
typedef const __attribute__((address_space(1))) void gv_t;
typedef __attribute__((address_space(3))) void lv_t;
__device__ __forceinline__ void cp16(const void* g, char* lds_dst) {
  __builtin_amdgcn_global_load_lds((gv_t*)g, (lv_t*)lds_dst, 16, 0, 0);
}

// ---------------- workspace layout (bytes) ----------------
#define WS_XH    0u           // 8192*512 f16            = 8,388,608
#define WS_W1T   8388608u     // 64*128*512 f16          = 8,388,608
#define WS_W2T   16777216u    // 64*64*128 f16           = 1,048,576
#define WS_W3T   17825792u    // 64*16*64 f16            =   131,072
#define WS_RWT   17956864u    // 64*512 f16              =    65,536
#define WS_P     18022400u    // 8192*64 f32             = 2,097,152
#define WS_NEED  20119552u

// ---------------- LDS layout for fused kernel (bytes) ----------------
#define H1S 136   // h1 row stride in halfs (128 + 8; stride%32dw==4 -> phased ok)
#define H2S 72    // h2 row stride in halfs (64 + 8)
#define LX   0        // x tile  [32 rows][512 halfs] unpadded, XOR-swizzled = 32768
#define LWB  32768    // W1 chunks [2][128 n][64 halfs] unpadded, swizzled   = 32768
#define LH1  65536    // h1 [32][136] f16                                    =  8704
#define LH2  74240    // h2 [32][72] f16                                     =  4608
#define LP   78848    // p  [32][16] f32                                     =  2048
#define LTOT 80896    // 79 KB -> 2 blocks/CU (158 KB of 160 KB)

// ============ convert x: fp32 -> f16 ============
__global__ __launch_bounds__(256) void convert_x(const float* __restrict__ x,
                                                 f16* __restrict__ xh) {
  int i = (blockIdx.x * 256 + threadIdx.x) * 4;
  float4 v = *(const float4*)(x + i);
  f16x4 h = {(f16)v.x, (f16)v.y, (f16)v.z, (f16)v.w};
  *(f16x4*)(xh + i) = h;
}

// ============ convert router_W [63][512] -> f16 [64][512] (row 63 zero) ============
__global__ __launch_bounds__(256) void convert_rwt(const float* __restrict__ rw,
                                                   f16* __restrict__ rwt) {
  int idx = blockIdx.x * 256 + threadIdx.x;   // 0..32767
  int n = idx >> 9;
  float v = 0.f;
  if (n < 63) v = rw[idx];
  rwt[idx] = (f16)v;
}

// ============ generic transpose: src fp32 [L][K][N] -> dst f16 [L][Npad][K] ============
__global__ __launch_bounds__(256) void transpose_wk(const float* __restrict__ src,
                                                    f16* __restrict__ dst,
                                                    int K, int N, int Npad) {
  __shared__ float tile[64][65];
  int k0 = blockIdx.x * 64;
  int l  = blockIdx.y;
  int n0 = blockIdx.z * 64;
  int t  = threadIdx.x;
  const float* s = src + ((size_t)l * K + k0) * N + n0;
#pragma unroll
  for (int i = 0; i < 16; ++i) {
    int idx = t + i * 256;
    int kk = idx >> 6, nn = idx & 63;
    float v = 0.f;
    if (n0 + nn < N) v = s[(size_t)kk * N + nn];
    tile[kk][nn] = v;
  }
  __syncthreads();
  f16* d = dst + ((size_t)l * Npad + n0) * K + k0;
#pragma unroll
  for (int i = 0; i < 16; ++i) {
    int idx = t + i * 256;
    int nn = idx >> 6, kk = idx & 63;
    if (n0 + nn < Npad) d[(size_t)nn * K + kk] = (f16)tile[kk][nn];
  }
}

// ============ router: logits (MFMA f16) -> sigmoid -> path products p[8192][64] ============
__global__ __launch_bounds__(256) void router_kernel(const f16* __restrict__ xh,
                                                     const f16* __restrict__ rwt,
                                                     const float* __restrict__ rb,
                                                     float* __restrict__ p_out) {
  __shared__ float route_s[64][64];
  const int t = threadIdx.x;
  const int wave = t >> 6, L = t & 63, quad = L >> 4, l16 = L & 15;
  const int b0 = blockIdx.x * 64;

  f32x4 acc[4];
#pragma unroll
  for (int nt = 0; nt < 4; ++nt) acc[nt] = (f32x4){0.f, 0.f, 0.f, 0.f};

  const f16* xrow = xh + (size_t)(b0 + wave * 16 + l16) * 512;
#pragma unroll 4
  for (int kk = 0; kk < 16; ++kk) {
    f16x8 a = *(const f16x8*)(xrow + kk * 32 + quad * 8);
#pragma unroll
    for (int nt = 0; nt < 4; ++nt) {
      f16x8 b = *(const f16x8*)(rwt + (size_t)(nt * 16 + l16) * 512 + kk * 32 + quad * 8);
      acc[nt] = MFMA16(a, b, acc[nt]);
    }
  }
#pragma unroll
  for (int nt = 0; nt < 4; ++nt) {
    int n = nt * 16 + l16;
    float bias = (n < 63) ? rb[n] : 0.f;
#pragma unroll
    for (int rg = 0; rg < 4; ++rg) {
      int r = wave * 16 + quad * 4 + rg;
      float logit = acc[nt][rg] + bias;
      route_s[r][n] = 1.f / (1.f + __expf(-logit));
    }
  }
  __syncthreads();
  int row = t >> 2, lq = t & 3;
#pragma unroll
  for (int j = 0; j < 16; ++j) {
    int l = lq * 16 + j;
    float prod = 1.f;
#pragma unroll
    for (int lev = 0; lev < 6; ++lev) {
      int node = (1 << lev) - 1 + (l >> (6 - lev));
      float d = route_s[row][node];
      prod *= ((l >> (5 - lev)) & 1) ? (1.f - d) : d;
    }
    p_out[(size_t)(b0 + row) * 64 + l] = prod;
  }
}

// ============ fused per-leaf MLP + weighted sum ============
// grid (256 batch-tiles of 32 rows, 4 leaf-groups of 16), 256 threads (4 waves)
__global__ __launch_bounds__(256, 2) void fused_tree(
    const f16* __restrict__ xh, const f16* __restrict__ w1t,
    const f16* __restrict__ w2t, const f16* __restrict__ w3t,
    const float* __restrict__ pglob, const float* __restrict__ b1,
    const float* __restrict__ b2, const float* __restrict__ b3,
    float* __restrict__ out) {
  extern __shared__ char smem[];
  f16*   x_lds  = (f16*)(smem + LX);
  f16*   wbuf   = (f16*)(smem + LWB);
  f16*   h1_lds = (f16*)(smem + LH1);
  f16*   h2_lds = (f16*)(smem + LH2);
  float* p_lds  = (float*)(smem + LP);

  const int t = threadIdx.x;
  const int w = t >> 6;              // wave 0..3
  const int L = t & 63;
  const int r31 = L & 31, kp = L >> 5;
  const int l16 = L & 15, quad = L >> 4;
  const int b0  = blockIdx.x * 32;
  const int lg0 = blockIdx.y * 16;

  // ---- stage x tile: 32 rows x 1 KB, one wave-issue per row, swizzled ----
  // LDS[r][u'] = X[r][u' xor-swz], u' in 16B units; swizzle on low 3 bits of unit.
#pragma unroll
  for (int j = 0; j < 8; ++j) {
    int r = w * 8 + j;
    int u = (L & 56) | ((L & 7) ^ (r & 7));
    cp16(xh + (size_t)(b0 + r) * 512 + u * 8, smem + LX + r * 1024);
  }
  // ---- stage p tile 32x16 ----
#pragma unroll
  for (int j = 0; j < 2; ++j) {
    int idx = t + j * 256;
    p_lds[idx] = pglob[(size_t)(b0 + (idx >> 4)) * 64 + lg0 + (idx & 15)];
  }

  // stage W1 chunk: [128 n][64 halfs], lane -> n = n0+(L>>3), unit u' = L&7,
  // source unit u = u' ^ (n&7). 4 wave-issues of 1 KB (8 n-rows) each.
  #define STAGE_W1(w1l_, kk_, buf_)                                            \
    {                                                                          \
      const f16* _src = (w1l_);                                                \
      _Pragma("unroll")                                                        \
      for (int j = 0; j < 4; ++j) {                                            \
        int n = (w * 4 + j) * 8 + (L >> 3);                                    \
        int u = (L & 7) ^ (n & 7);                                             \
        cp16(_src + (size_t)n * 512 + (kk_) * 64 + u * 8,                      \
             smem + LWB + (buf_) * 16384 + (w * 4 + j) * 1024);                \
      }                                                                        \
    }

  STAGE_W1(w1t + (size_t)lg0 * 65536, 0, 0);

  f32x4 acc_out = {0.f, 0.f, 0.f, 0.f};   // GEMM3 accumulator (waves 0,1)
  const int nn = w * 32 + r31;             // GEMM1 output column (H1 channel)
  const int nsw = nn & 7;
  __syncthreads();

#pragma unroll 1
  for (int li = 0; li < 16; ++li) {
    const int l = lg0 + li;
    const f16* w1l = w1t + (size_t)l * 65536;

    // ---- GEMM1: X(32x512) @ W1t[l] -> H1(32x128); wave tile 32x32, mfma32 ----
    f32x16 acc1;
#pragma unroll
    for (int i = 0; i < 16; ++i) acc1[i] = 0.f;

#pragma unroll
    for (int kk = 0; kk < 8; ++kk) {
      if (kk < 7)            STAGE_W1(w1l, kk + 1, (kk + 1) & 1)
      else if (li < 15)      STAGE_W1(w1l + 65536, 0, 0)
#pragma unroll
      for (int ks = 0; ks < 4; ++ks) {
        int ua = ks * 2 + kp;                       // within-chunk unit (0..7)
        f16x8 A = *(const f16x8*)(x_lds + r31 * 512 + kk * 64 + ((ua ^ (r31 & 7)) * 8));
        f16x8 B = *(const f16x8*)(wbuf + (kk & 1) * 8192 + nn * 64 + ((ua ^ nsw) * 8));
        acc1 = MFMA32(A, B, acc1);
      }
      __syncthreads();
    }

    // ---- H1 epilogue: +b1, relu, f16 -> h1_lds (C: col=L&31, row=(reg&3)+8*(reg>>2)+4*kp)
    {
      float bias = b1[l * 128 + nn];
#pragma unroll
      for (int reg = 0; reg < 16; ++reg) {
        int r = (reg & 3) + 8 * (reg >> 2) + 4 * kp;
        float v = acc1[reg] + bias;
        h1_lds[r * H1S + nn] = (f16)(v > 0.f ? v : 0.f);
      }
    }

    // prefetch GEMM2/GEMM3 B-fragments straight from global (L2)
    const int mt = w & 1, nh = w >> 1;
    f16x8 bw2[2][4];
#pragma unroll
    for (int nt = 0; nt < 2; ++nt)
#pragma unroll
      for (int ks = 0; ks < 4; ++ks)
        bw2[nt][ks] = *(const f16x8*)(w2t + (size_t)l * 8192 +
                                      (nh * 32 + nt * 16 + l16) * 128 + ks * 32 + quad * 8);
    f16x8 bw3[2];
    if (w < 2) {
#pragma unroll
      for (int ks = 0; ks < 2; ++ks)
        bw3[ks] = *(const f16x8*)(w3t + (size_t)l * 1024 + l16 * 64 + ks * 32 + quad * 8);
    }
    __syncthreads();

    // ---- GEMM2: H1(32x128) @ W2t[l] -> H2(32x64); wave tile 16x32 (16x16x32) ----
    f32x4 acc2[2] = {{0.f,0.f,0.f,0.f},{0.f,0.f,0.f,0.f}};
#pragma unroll
    for (int ks = 0; ks < 4; ++ks) {
      f16x8 A = *(const f16x8*)(h1_lds + (mt * 16 + l16) * H1S + ks * 32 + quad * 8);
#pragma unroll
      for (int nt = 0; nt < 2; ++nt)
        acc2[nt] = MFMA16(A, bw2[nt][ks], acc2[nt]);
    }
#pragma unroll
    for (int nt = 0; nt < 2; ++nt) {
      int n = nh * 32 + nt * 16 + l16;
      float bias = b2[l * 64 + n];
#pragma unroll
      for (int rg = 0; rg < 4; ++rg) {
        int r = mt * 16 + quad * 4 + rg;
        float v = acc2[nt][rg] + bias;
        v = v > 0.f ? v : 0.f;
        h2_lds[r * H2S + n] = (f16)(v * p_lds[r * 16 + li]);   // fold p into H2
      }
    }
    __syncthreads();

    // ---- GEMM3: H2'(32x64) @ W3t[l] -> acc_out (waves 0,1; cols 8..15 zero-pad)
    if (w < 2) {
#pragma unroll
      for (int ks = 0; ks < 2; ++ks) {
        f16x8 A = *(const f16x8*)(h2_lds + (w * 16 + l16) * H2S + ks * 32 + quad * 8);
        acc_out = MFMA16(A, bw3[ks], acc_out);
      }
    }
    // no extra barrier: next leaf's first LDS writes (wbuf) are disjoint from h2,
    // and h1/h2 rewrites are separated by >=1 barrier from here.
  }

  // ---- final epilogue: + sum_li p*b3, atomicAdd into out ----
  if (w < 2 && l16 < 8) {
    float b3v[16];
#pragma unroll
    for (int li2 = 0; li2 < 16; ++li2) b3v[li2] = b3[(lg0 + li2) * 8 + l16];
#pragma unroll
    for (int rg = 0; rg < 4; ++rg) {
      int r = w * 16 + quad * 4 + rg;
      float v = acc_out[rg];
#pragma unroll
      for (int li2 = 0; li2 < 16; ++li2) v += p_lds[r * 16 + li2] * b3v[li2];
      atomicAdd(out + (size_t)(b0 + r) * 8 + l16, v);
    }
  }
}

extern "C" void kernel_launch(void* const* d_in, const int* in_sizes, int n_in,
                              void* d_out, int out_size, void* d_ws, size_t ws_size,
                              hipStream_t stream) {
  const float* x  = (const float*)d_in[0];
  const float* rW = (const float*)d_in[1];
  const float* rb = (const float*)d_in[2];
  const float* W1 = (const float*)d_in[3];
  const float* b1 = (const float*)d_in[4];
  const float* W2 = (const float*)d_in[5];
  const float* b2 = (const float*)d_in[6];
  const float* W3 = (const float*)d_in[7];
  const float* b3 = (const float*)d_in[8];
  float* out = (float*)d_out;

  if (ws_size < WS_NEED) return;

  char* ws = (char*)d_ws;
  f16*   xh  = (f16*)(ws + WS_XH);
  f16*   w1t = (f16*)(ws + WS_W1T);
  f16*   w2t = (f16*)(ws + WS_W2T);
  f16*   w3t = (f16*)(ws + WS_W3T);
  f16*   rwt = (f16*)(ws + WS_RWT);
  float* p   = (float*)(ws + WS_P);

  hipMemsetAsync(d_out, 0, (size_t)out_size * sizeof(float), stream);

  convert_x<<<4096, 256, 0, stream>>>(x, xh);
  convert_rwt<<<128, 256, 0, stream>>>(rW, rwt);
  transpose_wk<<<dim3(8, 64, 2), 256, 0, stream>>>(W1, w1t, 512, 128, 128);
  transpose_wk<<<dim3(2, 64, 1), 256, 0, stream>>>(W2, w2t, 128, 64, 64);
  transpose_wk<<<dim3(1, 64, 1), 256, 0, stream>>>(W3, w3t, 64, 8, 16);
  router_kernel<<<128, 256, 0, stream>>>(xh, rwt, rb, p);

  (void)hipFuncSetAttribute(reinterpret_cast<const void*>(fused_tree),
                            hipFuncAttributeMaxDynamicSharedMemorySize, LTOT);
  fused_tree<<<dim3(256, 4), 256, LTOT, stream>>>(xh, w1t, w2t, w3t, p, b1, b2, b3, out);
}